// Round 8
// baseline (1904.269 us; speedup 1.0000x reference)
//
#include <hip/hip_runtime.h>
#include <hip/hip_bf16.h>
#include <cstdint>
#include <cstddef>

typedef __attribute__((ext_vector_type(4))) float floatx4;
typedef __attribute__((ext_vector_type(8))) short shortx8;
typedef __attribute__((ext_vector_type(2))) __fp16 f16x2;

#define T_SEQ 512
#define NIN   512
#define BATCH 256
#define HID   256
#define G3    768
#define NC    101

static __device__ __forceinline__ unsigned short f2bf(float f){
  unsigned int u = __float_as_uint(f);
  u += 0x7FFFu + ((u >> 16) & 1u);
  return (unsigned short)(u >> 16);
}

static __device__ __forceinline__ float dot2acc(f16x2 w, f16x2 h, float acc){
#if __has_builtin(__builtin_amdgcn_fdot2)
  return __builtin_amdgcn_fdot2(w, h, acc, false);
#else
  return acc + (float)w[0]*(float)h[0] + (float)w[1]*(float)h[1];
#endif
}

// ---------------- Phase A: xg[b*Tc+tt][n] = x[b, t0+tt, :] . Wih[n, :] + bih[n]
#define BM 128
#define BN 128
#define BK 64
#define LDK 72

__global__ __launch_bounds__(256) void gemm_xg(
    const float* __restrict__ x, const float* __restrict__ Wih,
    const float* __restrict__ bih, float* __restrict__ xg,
    int t0, int tcLog2)
{
  __shared__ unsigned short As[BM*LDK];
  __shared__ unsigned short Bs[BN*LDK];
  const int tid  = threadIdx.x;
  const int bn   = blockIdx.x;   // N fastest: 6 consecutive blocks share one x-tile
  const int bm   = blockIdx.y;
  const int w    = tid >> 6;
  const int l    = tid & 63;
  const int lm   = l & 15;
  const int quad = l >> 4;

  const int srow = tid >> 4;
  const int scol = (tid & 15) * 4;
  const int tcMask = (1 << tcLog2) - 1;

  floatx4 acc[2][8];
  #pragma unroll
  for (int mt = 0; mt < 2; ++mt)
    #pragma unroll
    for (int nt = 0; nt < 8; ++nt)
      acc[mt][nt] = (floatx4){0.f, 0.f, 0.f, 0.f};

  for (int kt = 0; kt < NIN / BK; ++kt){
    const int k0 = kt * BK;
    __syncthreads();
    #pragma unroll
    for (int p = 0; p < 8; ++p){
      const int r  = p * 16 + srow;
      const int gm = bm * BM + r;
      const int b  = gm >> tcLog2;
      const int tt = gm & tcMask;
      const float4 xa = *(const float4*)(x + (size_t)(b * T_SEQ + t0 + tt) * NIN + k0 + scol);
      union { unsigned short u[4]; uint2 v; } pa;
      pa.u[0] = f2bf(xa.x); pa.u[1] = f2bf(xa.y); pa.u[2] = f2bf(xa.z); pa.u[3] = f2bf(xa.w);
      *(uint2*)&As[r * LDK + scol] = pa.v;
      const int gn = bn * BN + r;
      const float4 wb = *(const float4*)(Wih + (size_t)gn * NIN + k0 + scol);
      union { unsigned short u[4]; uint2 v; } pb;
      pb.u[0] = f2bf(wb.x); pb.u[1] = f2bf(wb.y); pb.u[2] = f2bf(wb.z); pb.u[3] = f2bf(wb.w);
      *(uint2*)&Bs[r * LDK + scol] = pb.v;
    }
    __syncthreads();
    #pragma unroll
    for (int ks = 0; ks < 2; ++ks){
      const int kk = ks * 32 + quad * 8;
      shortx8 af[2], bfr[8];
      #pragma unroll
      for (int mt = 0; mt < 2; ++mt)
        af[mt] = *(const shortx8*)&As[(w * 32 + mt * 16 + lm) * LDK + kk];
      #pragma unroll
      for (int nt = 0; nt < 8; ++nt)
        bfr[nt] = *(const shortx8*)&Bs[(nt * 16 + lm) * LDK + kk];
      #pragma unroll
      for (int mt = 0; mt < 2; ++mt)
        #pragma unroll
        for (int nt = 0; nt < 8; ++nt)
          acc[mt][nt] = __builtin_amdgcn_mfma_f32_16x16x32_bf16(af[mt], bfr[nt], acc[mt][nt], 0, 0, 0);
    }
  }

  #pragma unroll
  for (int mt = 0; mt < 2; ++mt){
    #pragma unroll
    for (int nt = 0; nt < 8; ++nt){
      #pragma unroll
      for (int i = 0; i < 4; ++i){
        const int ml = w * 32 + mt * 16 + quad * 4 + i;
        const int nl = nt * 16 + lm;
        const int gm = bm * BM + ml;
        const int gn = bn * BN + nl;
        xg[(size_t)gm * G3 + gn] = acc[mt][nt][i] + bih[gn];
      }
    }
  }
}

// ---------------- Phase B: sequential GRU, full-K per thread, 1 wave/SIMD.
// 256 WGs x 256 threads. amdgpu_waves_per_eu(1,1) CLAMPS occupancy at
// 1 wave/SIMD -> 512-VGPR budget, so the 384 f16x2 weight registers stay
// in VGPRs (no AGPR shuffling — the R3..R7 failure mode).
// Thread j: Whh rows {j, j+256, j+512} as f16 pairs; all 3 gates for j.
// h: fp32 master in reg; f16 mirror in LDS, double-buffered (1 barrier/step).
__global__ __launch_bounds__(256, 1)
__attribute__((amdgpu_waves_per_eu(1, 1)))
void gru_steps(
    const float* __restrict__ xg, const float* __restrict__ Whh,
    const float* __restrict__ bhh, float* __restrict__ hstate,
    int Tc, int initFlag)
{
  __shared__ alignas(16) unsigned short hph[2][HID];  // packed f16 h, dbuf
  const int b = blockIdx.x;
  const int j = threadIdx.x;

  // 3 x 128 f16x2 = 384 VGPRs of weights.
  f16x2 wrr[128], wrz[128], wrn[128];
  {
    const float4* r4 = (const float4*)(Whh + (size_t)j * HID);
    const float4* z4 = (const float4*)(Whh + (size_t)(j + 256) * HID);
    const float4* n4 = (const float4*)(Whh + (size_t)(j + 512) * HID);
    #pragma unroll
    for (int k = 0; k < 64; ++k){
      float4 v = r4[k];
      wrr[2*k]   = __builtin_amdgcn_cvt_pkrtz(v.x, v.y);
      wrr[2*k+1] = __builtin_amdgcn_cvt_pkrtz(v.z, v.w);
    }
    #pragma unroll
    for (int k = 0; k < 64; ++k){
      float4 v = z4[k];
      wrz[2*k]   = __builtin_amdgcn_cvt_pkrtz(v.x, v.y);
      wrz[2*k+1] = __builtin_amdgcn_cvt_pkrtz(v.z, v.w);
    }
    #pragma unroll
    for (int k = 0; k < 64; ++k){
      float4 v = n4[k];
      wrn[2*k]   = __builtin_amdgcn_cvt_pkrtz(v.x, v.y);
      wrn[2*k+1] = __builtin_amdgcn_cvt_pkrtz(v.z, v.w);
    }
  }
  const float br = bhh[j];
  const float bz = bhh[j + 256];
  const float bn = bhh[j + 512];

  float hj = initFlag ? 0.f : hstate[b * HID + j];
  {
    union { __fp16 f; unsigned short u; } cv;
    cv.f = (__fp16)hj;
    hph[0][j] = cv.u;
  }
  __syncthreads();

  const float* xgrow = xg + (size_t)b * Tc * G3 + j;
  float xr = xgrow[0], xz = xgrow[256], xn = xgrow[512];

  #pragma unroll 1
  for (int t = 0; t < Tc; ++t){
    // Prefetch t+1 now: ~900 cyc of dot work before the barrier drain,
    // so the loads are nearly complete when (if) drained.
    const int tn = (t + 1 < Tc) ? (t + 1) : t;
    const float nxr = xgrow[(size_t)tn * G3];
    const float nxz = xgrow[(size_t)tn * G3 + 256];
    const float nxn = xgrow[(size_t)tn * G3 + 512];

    // Full-length dots: 32 broadcast b128 reads, rolling (no big preload).
    float ar0 = 0.f, ar1 = 0.f, az0 = 0.f, az1 = 0.f, an0 = 0.f, an1 = 0.f;
    const uint4* hp4 = (const uint4*)&hph[t & 1][0];
    #pragma unroll
    for (int i = 0; i < 32; ++i){
      const uint4 hv = hp4[i];
      union { unsigned int u; f16x2 h; } c0, c1, c2, c3;
      c0.u = hv.x; c1.u = hv.y; c2.u = hv.z; c3.u = hv.w;
      const int p = 4 * i;
      ar0 = dot2acc(wrr[p    ], c0.h, ar0);
      az0 = dot2acc(wrz[p    ], c0.h, az0);
      an0 = dot2acc(wrn[p    ], c0.h, an0);
      ar1 = dot2acc(wrr[p + 1], c1.h, ar1);
      az1 = dot2acc(wrz[p + 1], c1.h, az1);
      an1 = dot2acc(wrn[p + 1], c1.h, an1);
      ar0 = dot2acc(wrr[p + 2], c2.h, ar0);
      az0 = dot2acc(wrz[p + 2], c2.h, az0);
      an0 = dot2acc(wrn[p + 2], c2.h, an0);
      ar1 = dot2acc(wrr[p + 3], c3.h, ar1);
      az1 = dot2acc(wrz[p + 3], c3.h, az1);
      an1 = dot2acc(wrn[p + 3], c3.h, an1);
    }
    const float hr = ar0 + ar1 + br;
    const float hz = az0 + az1 + bz;
    const float hn = an0 + an1 + bn;

    const float r = 1.f / (1.f + __expf(-(xr + hr)));
    const float z = 1.f / (1.f + __expf(-(xz + hz)));
    const float a = xn + r * hn;
    const float ex = __expf(-2.f * fabsf(a));
    float n = (1.f - ex) / (1.f + ex);
    n = copysignf(n, a);
    const float hnew = fmaf(z, hj - n, n);   // (1-z)*n + z*h

    hj = hnew;
    {
      union { __fp16 f; unsigned short u; } cv;
      cv.f = (__fp16)hj;
      hph[1 - (t & 1)][j] = cv.u;   // write the other buffer: no read race
    }
    __syncthreads();                // single barrier per step
    xr = nxr; xz = nxz; xn = nxn;
  }

  hstate[b * HID + j] = hj;
}

// ---------------- FC
__global__ __launch_bounds__(128) void fc_kernel(
    const float* __restrict__ hstate, const float* __restrict__ fw,
    const float* __restrict__ fb, float* __restrict__ out)
{
  __shared__ float hs[HID];
  const int b = blockIdx.x;
  const int t = threadIdx.x;
  hs[t]       = hstate[b * HID + t];
  hs[t + 128] = hstate[b * HID + t + 128];
  __syncthreads();
  if (t < NC){
    float acc = fb[t];
    const float4* w4 = (const float4*)(fw + (size_t)t * HID);
    const float4* h4 = (const float4*)hs;
    #pragma unroll
    for (int k = 0; k < 64; ++k){
      const float4 wv = w4[k];
      const float4 hv = h4[k];
      acc += wv.x * hv.x + wv.y * hv.y + wv.z * hv.z + wv.w * hv.w;
    }
    out[b * NC + t] = acc;
  }
}

extern "C" void kernel_launch(void* const* d_in, const int* in_sizes, int n_in,
                              void* d_out, int out_size, void* d_ws, size_t ws_size,
                              hipStream_t stream)
{
  const float* x   = (const float*)d_in[0];
  const float* Wih = (const float*)d_in[1];
  const float* Whh = (const float*)d_in[2];
  const float* bih = (const float*)d_in[3];
  const float* bhh = (const float*)d_in[4];
  const float* fcw = (const float*)d_in[5];
  const float* fcb = (const float*)d_in[6];
  float* out = (float*)d_out;

  float* hst = (float*)d_ws;
  const size_t hBytes = (size_t)BATCH * HID * sizeof(float);
  float* xg  = (float*)((char*)d_ws + hBytes);

  const size_t perT = (size_t)BATCH * G3 * sizeof(float);
  const size_t avail = (ws_size > hBytes) ? (ws_size - hBytes) : 0;
  int tcLog2 = 9;
  while (tcLog2 > 0 && perT * ((size_t)1 << tcLog2) > avail) --tcLog2;
  const int Tc = 1 << tcLog2;

  for (int t0 = 0; t0 < T_SEQ; t0 += Tc){
    dim3 grid(6, 2 * Tc);
    gemm_xg<<<grid, 256, 0, stream>>>(x, Wih, bih, xg, t0, tcLog2);
    gru_steps<<<BATCH, 256, 0, stream>>>(xg, Whh, bhh, hst, Tc, (t0 == 0) ? 1 : 0);
  }
  fc_kernel<<<BATCH, 128, 0, stream>>>(hst, fcw, fcb, out);
}